// Round 10
// baseline (37.417 us; speedup 1.0000x reference)
//
#include <hip/hip_runtime.h>
#include <hip/hip_bf16.h>

typedef __bf16 bf16x8 __attribute__((ext_vector_type(8)));
typedef float f32x4 __attribute__((ext_vector_type(4)));

#define G 8
#define B 32
#define D 32
#define O 32
#define K 4096   // N*T (floats per W row)
#define T 64
#define KSPLIT 2
#define KCHUNK (K / KSPLIT)   // 2048 floats
#define BK 256                // floats staged per row per step (1KB burst)
#define NSTEP (KCHUNK / BK)   // 8
#define MROWS 16              // o-rows per block

// ws: XB bf16 [K/32][B][32] = 256 KB only.
#define XB_ELEMS (B * K)

// Fused prep: threads [0,16384) build XB (MFMA B-frag order, no mask);
// threads [16384, 49152) init out[b][d][o] = bias[d][o] (gemm atomically adds).
__global__ __launch_bounds__(256) void prep_and_init(const float* __restrict__ x,
                                                     const float* __restrict__ bias,
                                                     __bf16* __restrict__ xb,
                                                     float* __restrict__ out) {
    int tid = blockIdx.x * 256 + threadIdx.x;
    if (tid < 16384) {
        int b = (tid >> 2) & 31;
        int k = (tid >> 7) * 32 + (tid & 3) * 8;
        const float4 x0 = *(const float4*)(x + b * K + k);
        const float4 x1 = *(const float4*)(x + b * K + k + 4);
        bf16x8 r;
        r[0] = (__bf16)x0.x; r[1] = (__bf16)x0.y; r[2] = (__bf16)x0.z; r[3] = (__bf16)x0.w;
        r[4] = (__bf16)x1.x; r[5] = (__bf16)x1.y; r[6] = (__bf16)x1.z; r[7] = (__bf16)x1.w;
        *(bf16x8*)(xb + (size_t)tid * 8) = r;   // flat idx == tid*8: coalesced
    } else {
        int t2 = tid - 16384;           // 32768 = B*D*O, out flat = b*1024 + d*32 + o
        out[t2] = bias[t2 & 1023];
    }
}

// Block (d, g, oh, ks) = ONE WAVE, zero barriers. M = 16 contiguous o-rows,
// N = 32 b (two 16x16x32 MFMAs per k-tile), K-half ks.
// LDS 2 x 16 KB double buffer; W staged via global_load_lds, 1KB contiguous
// burst per o-row; XOR chunk-swizzle (row&7)<<4 on source AND read (rule 21).
// Single-wave pipeline: s_waitcnt vmcnt(16) retires {XLOAD(cur), STAGE(cur)}
// while STAGE(next)'s 16 loads stay in flight through compute. No s_barrier,
// no inter-wave coupling: 5 blocks/CU (LDS-bound) + backfill keep demand smooth.
// mask[o][t] applied to the A-fragment before bf16 convert.
// Epilogue: out[b][d][o] += y[b][g] * acc  (unsafeAtomicAdd, 16 adders/elem).
__global__ __launch_bounds__(64) void gemm_main(const float* __restrict__ W,
                                                const __bf16* __restrict__ xb,
                                                const float* __restrict__ mask,
                                                const float* __restrict__ y,
                                                float* __restrict__ out) {
    __shared__ float ldsW[2][MROWS * BK];   // 2 x 16 KB
    const int d = blockIdx.x, g = blockIdx.y;
    const int oh = blockIdx.z & 1, ks = blockIdx.z >> 1;
    const int lane = threadIdx.x;
    const int l15 = lane & 15, g16 = lane >> 4;

    // A-fragment read: local row = l15, byte = s*128 + g16*32 (^16 hi), swizzled
    const int lds_ro = l15 * 1024 + ((g16 * 32) ^ ((l15 & 7) * 16));

    // mask row o = oh*16 + l15; lane needs t = (s&1)*32 + g16*8 + j
    const float* mrow = mask + (oh * 16 + l15) * T + g16 * 8;
    const float4 me0 = *(const float4*)(mrow);
    const float4 me1 = *(const float4*)(mrow + 4);
    const float4 mo0 = *(const float4*)(mrow + 32);
    const float4 mo1 = *(const float4*)(mrow + 36);

    // XB: k-tile kt = ks*64 + step*8 + s; elem = kt*1024 + b*32 + g16*8
    const __bf16* xbl = xb + (size_t)(ks * (KCHUNK / 32)) * 1024 + l15 * 32 + g16 * 8;

    // W rows for this block: o = oh*16 + 0..15, contiguous
    const size_t wrow0 = ((size_t)(g * D + d) * O + oh * 16) * K + (size_t)ks * KCHUNK;

    f32x4 acc0 = {0.f, 0.f, 0.f, 0.f};
    f32x4 acc1 = {0.f, 0.f, 0.f, 0.f};

#define STAGE(buf, step)                                                          \
    {                                                                             \
        _Pragma("unroll")                                                         \
        for (int i = 0; i < MROWS; ++i) {                                         \
            const char* src = (const char*)(W + wrow0 + (size_t)i * K             \
                                            + (size_t)(step) * BK)                \
                              + ((lane * 16) ^ ((i & 7) * 16));                   \
            __builtin_amdgcn_global_load_lds(                                     \
                (const __attribute__((address_space(1))) void*)src,               \
                (__attribute__((address_space(3))) void*)((char*)&ldsW[buf][0]    \
                                                          + i * 1024),            \
                16, 0, 0);                                                        \
        }                                                                         \
    }

    bf16x8 xr[2][8];   // [b-half][k-tile], prefetched 1 step ahead
#define XLOAD(step)                                                               \
    {                                                                             \
        _Pragma("unroll")                                                         \
        for (int h = 0; h < 2; ++h)                                               \
            _Pragma("unroll")                                                     \
            for (int s = 0; s < 8; ++s)                                           \
                xr[h][s] = *(const bf16x8*)(xbl + (size_t)(step) * 8192           \
                                                + (size_t)s * 1024 + h * 512);    \
    }

    STAGE(0, 0);

    #pragma unroll
    for (int step = 0; step < NSTEP; ++step) {
        const int cur = step & 1;

        XLOAD(step);                         // 16 loads, older than next stage
        __builtin_amdgcn_sched_barrier(0);
        if (step + 1 < NSTEP) {
            STAGE(cur ^ 1, step + 1);        // 16 loads, in flight all step
            __builtin_amdgcn_sched_barrier(0);
            asm volatile("s_waitcnt vmcnt(16)" ::: "memory"); // cur stage+xb done
        } else {
            __builtin_amdgcn_sched_barrier(0);
            asm volatile("s_waitcnt vmcnt(0)" ::: "memory");
        }
        __builtin_amdgcn_sched_barrier(0);

        const char* lb = (const char*)&ldsW[cur][0];
        #pragma unroll
        for (int s = 0; s < 8; ++s) {
            const int a0 = lds_ro + s * 128;
            const f32x4 alo = *(const f32x4*)(lb + a0);
            const f32x4 ahi = *(const f32x4*)(lb + (a0 ^ 16));
            const float4 ms0 = (s & 1) ? mo0 : me0;
            const float4 ms1 = (s & 1) ? mo1 : me1;
            bf16x8 af;
            af[0] = (__bf16)(alo[0] * ms0.x); af[1] = (__bf16)(alo[1] * ms0.y);
            af[2] = (__bf16)(alo[2] * ms0.z); af[3] = (__bf16)(alo[3] * ms0.w);
            af[4] = (__bf16)(ahi[0] * ms1.x); af[5] = (__bf16)(ahi[1] * ms1.y);
            af[6] = (__bf16)(ahi[2] * ms1.z); af[7] = (__bf16)(ahi[3] * ms1.w);
            acc0 = __builtin_amdgcn_mfma_f32_16x16x32_bf16(af, xr[0][s], acc0, 0, 0, 0);
            acc1 = __builtin_amdgcn_mfma_f32_16x16x32_bf16(af, xr[1][s], acc1, 0, 0, 0);
        }
        __builtin_amdgcn_sched_barrier(0);   // all ds_reads of cur consumed here
    }
#undef STAGE
#undef XLOAD

    // C/D: lane holds D[row=g16*4+i][col=l15]; row = o-local, col = b-local
    const float yv0 = y[l15 * G + g];
    const float yv1 = y[(16 + l15) * G + g];
    float* op0 = out + l15 * (D * O) + d * O + oh * 16 + g16 * 4;
    float* op1 = op0 + 16 * (D * O);
    #pragma unroll
    for (int i = 0; i < 4; ++i) {
        unsafeAtomicAdd(op0 + i, yv0 * acc0[i]);
        unsafeAtomicAdd(op1 + i, yv1 * acc1[i]);
    }
}

extern "C" void kernel_launch(void* const* d_in, const int* in_sizes, int n_in,
                              void* d_out, int out_size, void* d_ws, size_t ws_size,
                              hipStream_t stream) {
    const float* x    = (const float*)d_in[0];
    const float* y    = (const float*)d_in[1];
    const float* w    = (const float*)d_in[2];
    const float* bias = (const float*)d_in[3];
    const float* mask = (const float*)d_in[4];
    float* out = (float*)d_out;

    __bf16* xbp = (__bf16*)d_ws;

    prep_and_init<<<192, 256, 0, stream>>>(x, bias, xbp, out);
    gemm_main<<<dim3(D, G, 4), 64, 0, stream>>>(w, xbp, mask, y, out);
}